// Round 3
// baseline (1084.022 us; speedup 1.0000x reference)
//
#include <hip/hip_runtime.h>
#include <stdint.h>

#define DEVI __device__ __forceinline__

typedef __attribute__((ext_vector_type(4))) int    i32x4;
typedef __attribute__((ext_vector_type(4))) float  f32x4;
typedef __attribute__((ext_vector_type(8))) __bf16 bf16x8;

static constexpr int BB = 4, NN = 2048, KK = 32, PP = NN * KK;  // P per batch
static constexpr float GEPS = 1e-5f;

DEVI unsigned short f2bf(float f) {
  unsigned u = __builtin_bit_cast(unsigned, f);
  return (unsigned short)((u + 0x7FFFu + ((u >> 16) & 1u)) >> 16);
}
DEVI float bf2f(unsigned short h) {
  unsigned u = (unsigned)h << 16;
  return __builtin_bit_cast(float, u);
}
DEVI uint2 pack4(float a, float b, float c, float d) {
  return make_uint2((unsigned)f2bf(a) | ((unsigned)f2bf(b) << 16),
                    (unsigned)f2bf(c) | ((unsigned)f2bf(d) << 16));
}
DEVI void mfma16(f32x4& d, i32x4 a, i32x4 b) {
  // A[m=lane&15][k=8*(lane>>4)+j], B[k][n=lane&15], D[m=(lane>>4)*4+reg][n=lane&15].
  d = __builtin_amdgcn_mfma_f32_16x16x32_bf16(
      __builtin_bit_cast(bf16x8, a), __builtin_bit_cast(bf16x8, b), d, 0, 0, 0);
}

// ---------------- prep: convert f32 weights to bf16 ----------------
__global__ void prep_kern(const float* Wfc, const float* Wgc, const float* Wfo,
                          unsigned short* dWfc, unsigned short* dWgc, unsigned short* dWfo) {
  int i = blockIdx.x * 256 + threadIdx.x;
  if (i < 16384)       dWfc[i] = f2bf(Wfc[i]);
  else if (i < 32768)  dWgc[i - 16384] = f2bf(Wgc[i - 16384]);
  else if (i < 98304)  dWfo[i - 32768] = f2bf(Wfo[i - 32768]);
}

// ---------------- generic fused GEMM ----------------
// out[b][p][COUT] (bf16) = act( W[COUT][CIN] @ in[b][CIN][p]  + bias )
// MODE 0: srcA = f32 channel-major input [b][CIN][P]; transposed+packed to LDS
//         via conflict-free 8ch x 4pos b128 writes.
// MODE 1: srcA = r1 bf16 [b][n][128] (broadcast over k), srcB = r2 bf16 [b][p][128].
//         LDS-free: B-fragments read direct from global (wave-identical -> L1).
//         W/bias per-batch (folded).
// A (weights) streamed per-ks from global (L2-hot: W << 4MB, reused every tile).
template<int CIN, int COUT, int MODE, bool RELU>
__global__ __launch_bounds__(256, MODE == 1 ? 4 : 3)
void gemm_kern(const void* srcA, const void* srcB,
               const unsigned short* Wmat, const float* bias,
               unsigned short* out, float* stats, int group_base,
               int P, int tiles_per_b, int nblk) {
  constexpr int MW = COUT / 4;    // o-range per wave
  constexpr int MF = MW / 16;     // m-fragments per wave
  constexpr int KS = CIN / 32;    // k-steps
  constexpr int CINP = CIN + 8;   // padded LDS pitch (shorts); rows 16B-aligned
  __shared__ unsigned short tile[(MODE == 0) ? 64 * CINP : 16];

  const int tid = threadIdx.x;
  const int lane = tid & 63, w = tid >> 6;
  const int l15 = lane & 15, lg = lane >> 4;
  const int b = blockIdx.x / nblk, blk = blockIdx.x % nblk;

  const unsigned short* Wb = (MODE == 1) ? (Wmat + (size_t)b * COUT * CIN) : Wmat;
  const float* biasb = (MODE == 1) ? (bias + b * COUT) : bias;
  const unsigned short* r1b = (const unsigned short*)srcA + (size_t)b * NN * 128;
  const unsigned short* r2b = (const unsigned short*)srcB + (size_t)b * PP * 128;

  f32x4 bi[MF];
#pragma unroll
  for (int mf = 0; mf < MF; ++mf)
    bi[mf] = *(const f32x4*)(biasb + w * MW + mf * 16 + lg * 4);

  float ssum[MF], ssq[MF];
#pragma unroll
  for (int mf = 0; mf < MF; ++mf) { ssum[mf] = 0.f; ssq[mf] = 0.f; }

  for (int t = blk; t < tiles_per_b; t += nblk) {
    const int p0 = t * 64;
    if (MODE == 0) {
      // transpose-stage: thread packs 8 channels x 4 positions -> b128 writes
      const float* src = (const float*)srcA + (size_t)b * CIN * P + p0;
      const int c16 = tid >> 4, pq = tid & 15;
#pragma unroll
      for (int pass = 0; pass < CIN / 128; ++pass) {
        const int c0 = pass * 128 + c16 * 8;
        f32x4 v[8];
#pragma unroll
        for (int i = 0; i < 8; ++i)
          v[i] = *(const f32x4*)(src + (size_t)(c0 + i) * (size_t)P + pq * 4);
#pragma unroll
        for (int jj = 0; jj < 4; ++jj) {
          uint2 lo = pack4(v[0][jj], v[1][jj], v[2][jj], v[3][jj]);
          uint2 hi = pack4(v[4][jj], v[5][jj], v[6][jj], v[7][jj]);
          uint4 q = make_uint4(lo.x, lo.y, hi.x, hi.y);
          *(uint4*)&tile[(pq * 4 + jj) * CINP + c0] = q;
        }
      }
      __syncthreads();
    }

    f32x4 acc[MF][4];
#pragma unroll
    for (int mf = 0; mf < MF; ++mf)
#pragma unroll
      for (int nf = 0; nf < 4; ++nf) acc[mf][nf] = f32x4{0.f, 0.f, 0.f, 0.f};

#pragma unroll
    for (int ks = 0; ks < KS; ++ks) {
      i32x4 a4[MF], b4[4];
#pragma unroll
      for (int mf = 0; mf < MF; ++mf)
        a4[mf] = *(const i32x4*)(Wb + (size_t)(w * MW + mf * 16 + l15) * CIN + ks * 32 + lg * 8);
      if (MODE == 0) {
#pragma unroll
        for (int nf = 0; nf < 4; ++nf)
          b4[nf] = *(const i32x4*)&tile[(nf * 16 + l15) * CINP + ks * 32 + lg * 8];
      } else {
#pragma unroll
        for (int nf = 0; nf < 4; ++nf) {
          if (ks < 4) {
            const int n = (p0 >> 5) + (nf >> 1);  // p0 is 64-aligned
            b4[nf] = *(const i32x4*)(r1b + (size_t)n * 128 + ks * 32 + lg * 8);
          } else {
            b4[nf] = *(const i32x4*)(r2b + (size_t)(p0 + nf * 16 + l15) * 128 +
                                     (ks - 4) * 32 + lg * 8);
          }
        }
      }
#pragma unroll
      for (int mf = 0; mf < MF; ++mf)
#pragma unroll
        for (int nf = 0; nf < 4; ++nf) mfma16(acc[mf][nf], a4[mf], b4[nf]);
    }
    if (MODE == 0) __syncthreads();

    // epilogue: bias (+relu), stats partials, packed bf16 store (pos-major)
#pragma unroll
    for (int mf = 0; mf < MF; ++mf) {
      const int o4 = w * MW + mf * 16 + lg * 4;
#pragma unroll
      for (int nf = 0; nf < 4; ++nf) {
        const int p = p0 + nf * 16 + l15;
        float y0 = acc[mf][nf][0] + bi[mf][0];
        float y1 = acc[mf][nf][1] + bi[mf][1];
        float y2 = acc[mf][nf][2] + bi[mf][2];
        float y3 = acc[mf][nf][3] + bi[mf][3];
        if (RELU) {
          y0 = fmaxf(y0, 0.f); y1 = fmaxf(y1, 0.f);
          y2 = fmaxf(y2, 0.f); y3 = fmaxf(y3, 0.f);
        }
        ssum[mf] += y0 + y1 + y2 + y3;
        ssq[mf] += y0 * y0 + y1 * y1 + y2 * y2 + y3 * y3;
        *(uint2*)(out + ((size_t)b * P + p) * COUT + o4) = pack4(y0, y1, y2, y3);
      }
    }
  }

  // block-level stats reduction -> global atomics
#pragma unroll
  for (int mf = 0; mf < MF; ++mf) {
    float s = ssum[mf], q = ssq[mf];
#pragma unroll
    for (int d = 1; d < 16; d <<= 1) { s += __shfl_xor(s, d); q += __shfl_xor(q, d); }
    if (l15 == 0) {
      int g = group_base + ((w * MW + mf * 16 + lg * 4) >> 3);
      atomicAdd(&stats[(b * 32 + g) * 2 + 0], s);
      atomicAdd(&stats[(b * 32 + g) * 2 + 1], q);
    }
  }
}

// ---------------- fold kernels ----------------
__global__ void fold1_kern(const float* st1, const float* g1, const float* be1,
                           const float* W_w1, const float* b_w1,
                           unsigned short* W1p, float* b1p) {
  int b = blockIdx.x, tid = threadIdx.x;
  __shared__ float s_l[256], t_l[256];
  {
    int c = tid, g = c >> 3;
    float cnt = (g < 16) ? (8.f * NN) : (8.f * NN * KK);
    float su = st1[(b * 32 + g) * 2], sq = st1[(b * 32 + g) * 2 + 1];
    float mean = su / cnt;
    float var = fmaxf(sq / cnt - mean * mean, 0.f);
    float s = g1[c] * rsqrtf(var + GEPS);
    s_l[c] = s; t_l[c] = be1[c] - mean * s;
  }
  __syncthreads();
  int o = tid;
  float acc = b_w1[o];
  for (int c = 0; c < 256; ++c) {
    float wv = W_w1[o * 256 + c];
    W1p[((size_t)b * 256 + o) * 256 + c] = f2bf(wv * s_l[c]);
    acc += wv * t_l[c];
  }
  b1p[b * 256 + o] = acc;
}

__global__ void fold23_kern(const float* st2, const float* st3,
                            const float* g2, const float* be2,
                            const float* W_w2, const float* b_w2,
                            const float* g3, const float* be3,
                            unsigned short* W2p, float* b2p, float* s3t3) {
  int b = blockIdx.x, tid = threadIdx.x;
  __shared__ float s_l[256], t_l[256];
  {
    int c = tid, g = c >> 3;
    float cnt = 8.f * NN * KK;
    float su = st2[(b * 32 + g) * 2], sq = st2[(b * 32 + g) * 2 + 1];
    float mean = su / cnt;
    float var = fmaxf(sq / cnt - mean * mean, 0.f);
    float s = g2[c] * rsqrtf(var + GEPS);
    s_l[c] = s; t_l[c] = be2[c] - mean * s;

    float su3 = st3[(b * 32 + g) * 2], sq3 = st3[(b * 32 + g) * 2 + 1];
    float mean3 = su3 / cnt;
    float var3 = fmaxf(sq3 / cnt - mean3 * mean3, 0.f);
    float s3 = g3[c] * rsqrtf(var3 + GEPS);
    s3t3[(b * 256 + c) * 2 + 0] = s3;
    s3t3[(b * 256 + c) * 2 + 1] = be3[c] - mean3 * s3;
  }
  __syncthreads();
  int o = tid;
  float acc = b_w2[o];
  for (int c = 0; c < 256; ++c) {
    float wv = W_w2[o * 256 + c];
    W2p[((size_t)b * 256 + o) * 256 + c] = f2bf(wv * s_l[c]);
    acc += wv * t_l[c];
  }
  b2p[b * 256 + o] = acc;
}

// ---------------- K5: scores GEMM + masked softmax + weighted sum ----------------
// x2 A-frags direct from global (wave-identical -> L1); W streamed per-ks;
// gor tile staged in LDS (coalesced fetch, scalar LDS reads in epilogue).
__global__ __launch_bounds__(256, 3)
void k5_kern(const unsigned short* x2t, const unsigned short* gor,
             const unsigned short* W2p, const float* b2p,
             const float* s3t3, const int* count, float* out, int nblk) {
  constexpr int GP = 272;  // pitch: rows 544B (16B-aligned), conflict-free b128 writes
  __shared__ unsigned short gt[64 * GP];
  const int tid = threadIdx.x, lane = tid & 63, w = tid >> 6;
  const int l15 = lane & 15, lg = lane >> 4;
  const int b = blockIdx.x / nblk, blk = blockIdx.x % nblk;

  const unsigned short* Wb = W2p + (size_t)b * 65536;

  float bia[4], s3v[4], t3v[4];
#pragma unroll
  for (int of = 0; of < 4; ++of) {
    int o = w * 64 + of * 16 + l15;
    bia[of] = b2p[b * 256 + o];
    s3v[of] = s3t3[(b * 256 + o) * 2 + 0];
    t3v[of] = s3t3[(b * 256 + o) * 2 + 1];
  }

  const unsigned short* xb = x2t + (size_t)b * PP * 256;
  const unsigned short* gb = gor + (size_t)b * PP * 256;

  for (int t = blk; t < 1024; t += nblk) {
    const int p0 = t * 64, n0 = p0 >> 5;

    // stage gor tile [64][256] -> gt (coalesced 16B chunks)
    {
      const unsigned short* gsrc = gb + (size_t)p0 * 256;
      const int cg = tid & 15, pr4 = (tid >> 4) * 4;
#pragma unroll
      for (int j = 0; j < 4; ++j) {
        const int p = pr4 + j;
        uint4 q0 = *(const uint4*)(gsrc + (size_t)p * 256 + cg * 8);
        uint4 q1 = *(const uint4*)(gsrc + (size_t)p * 256 + 128 + cg * 8);
        *(uint4*)&gt[p * GP + cg * 8] = q0;
        *(uint4*)&gt[p * GP + 128 + cg * 8] = q1;
      }
    }
    __syncthreads();

    f32x4 acc[4][4];  // [pf][of]
#pragma unroll
    for (int pf = 0; pf < 4; ++pf)
#pragma unroll
      for (int of = 0; of < 4; ++of) acc[pf][of] = f32x4{0.f, 0.f, 0.f, 0.f};

#pragma unroll
    for (int ks = 0; ks < 8; ++ks) {
      i32x4 af[4], wf[4];
#pragma unroll
      for (int pf = 0; pf < 4; ++pf)
        af[pf] = *(const i32x4*)(xb + (size_t)(p0 + pf * 16 + l15) * 256 + ks * 32 + lg * 8);
#pragma unroll
      for (int of = 0; of < 4; ++of)
        wf[of] = *(const i32x4*)(Wb + (size_t)(w * 64 + of * 16 + l15) * 256 + ks * 32 + lg * 8);
#pragma unroll
      for (int pf = 0; pf < 4; ++pf)
#pragma unroll
        for (int of = 0; of < 4; ++of) mfma16(acc[pf][of], af[pf], wf[of]);
    }

    const int cnt0 = max(count[b * NN + n0], 1);
    const int cnt1 = max(count[b * NN + n0 + 1], 1);
#pragma unroll
    for (int of = 0; of < 4; ++of) {
      const int o = w * 64 + of * 16 + l15;
      float res[2];
#pragma unroll
      for (int pair = 0; pair < 2; ++pair) {
        const int cnt = pair ? cnt1 : cnt0;
        float sc[2][4];
#pragma unroll
        for (int ph = 0; ph < 2; ++ph)
#pragma unroll
          for (int r = 0; r < 4; ++r) {
            int k = ph * 16 + lg * 4 + r;
            float v = acc[pair * 2 + ph][of][r] + bia[of];
            sc[ph][r] = (k < cnt) ? v : -1e9f;
          }
        float m = sc[0][0];
#pragma unroll
        for (int ph = 0; ph < 2; ++ph)
#pragma unroll
          for (int r = 0; r < 4; ++r) m = fmaxf(m, sc[ph][r]);
        m = fmaxf(m, __shfl_xor(m, 16));
        m = fmaxf(m, __shfl_xor(m, 32));
        float den = 0.f, con = 0.f;
#pragma unroll
        for (int ph = 0; ph < 2; ++ph)
#pragma unroll
          for (int r = 0; r < 4; ++r) {
            float e = __expf(sc[ph][r] - m);
            int prel = pair * 32 + ph * 16 + lg * 4 + r;
            float g = bf2f(gt[prel * GP + o]);
            g = fmaxf(s3v[of] * g + t3v[of], 0.f);
            den += e; con += e * g;
          }
        den += __shfl_xor(den, 16); con += __shfl_xor(con, 16);
        den += __shfl_xor(den, 32); con += __shfl_xor(con, 32);
        res[pair] = con / den;
      }
      if (lg == 0)
        *(float2*)(out + (size_t)(b * 256 + o) * NN + n0) = make_float2(res[0], res[1]);
    }
    __syncthreads();  // gt consumed; safe to restage next tile
  }
}

// ---------------- launch ----------------
extern "C" void kernel_launch(void* const* d_in, const int* in_sizes, int n_in,
                              void* d_out, int out_size, void* d_ws, size_t ws_size,
                              hipStream_t stream) {
  const float* feat = (const float*)d_in[0];
  const float* gf   = (const float*)d_in[1];
  const float* gfo  = (const float*)d_in[2];
  const int*   cnt  = (const int*)d_in[3];
  const float* W_fc = (const float*)d_in[4];
  const float* b_fc = (const float*)d_in[5];
  const float* W_gc = (const float*)d_in[6];
  const float* b_gc = (const float*)d_in[7];
  const float* g1   = (const float*)d_in[8];
  const float* be1  = (const float*)d_in[9];
  const float* W_w1 = (const float*)d_in[10];
  const float* b_w1 = (const float*)d_in[11];
  const float* g2   = (const float*)d_in[12];
  const float* be2  = (const float*)d_in[13];
  const float* W_w2 = (const float*)d_in[14];
  const float* b_w2 = (const float*)d_in[15];
  const float* W_fo = (const float*)d_in[16];
  const float* b_fo = (const float*)d_in[17];
  const float* g3   = (const float*)d_in[18];
  const float* be3  = (const float*)d_in[19];
  float* out = (float*)d_out;
  char* ws = (char*)d_ws;

  constexpr size_t ST1 = 0, ST2 = 1024, ST3 = 2048;
  constexpr size_t WFC = 4096;
  constexpr size_t WGC = WFC + 32768;
  constexpr size_t WFO = WGC + 32768;
  constexpr size_t W1P = WFO + 131072;
  constexpr size_t B1P = W1P + 524288;
  constexpr size_t W2P = B1P + 4096;
  constexpr size_t B2P = W2P + 524288;
  constexpr size_t S3T = B2P + 4096;
  constexpr size_t R1  = 2097152;
  constexpr size_t X2  = R1 + 2097152;
  constexpr size_t R2  = X2 + 134217728;
  constexpr size_t GOR = R2;  // go_raw overwrites r2 (written after K4 consumed r2)
  constexpr size_t WS_NEED = GOR + 134217728;
  if (ws_size < WS_NEED) return;

  float* st1 = (float*)(ws + ST1);
  float* st2 = (float*)(ws + ST2);
  float* st3 = (float*)(ws + ST3);
  unsigned short* wfc = (unsigned short*)(ws + WFC);
  unsigned short* wgc = (unsigned short*)(ws + WGC);
  unsigned short* wfo = (unsigned short*)(ws + WFO);
  unsigned short* w1p = (unsigned short*)(ws + W1P);
  float* b1p = (float*)(ws + B1P);
  unsigned short* w2p = (unsigned short*)(ws + W2P);
  float* b2p = (float*)(ws + B2P);
  float* s3t = (float*)(ws + S3T);
  unsigned short* r1 = (unsigned short*)(ws + R1);
  unsigned short* x2 = (unsigned short*)(ws + X2);
  unsigned short* r2 = (unsigned short*)(ws + R2);
  unsigned short* gor = (unsigned short*)(ws + GOR);

  hipMemsetAsync(ws, 0, 3072, stream);
  prep_kern<<<384, 256, 0, stream>>>(W_fc, W_gc, W_fo, wfc, wgc, wfo);

  // K1: feat1 = relu(W_fc@feat+b) -> r1 [b][n][128], stats1 groups 0..15
  gemm_kern<128, 128, 0, true><<<dim3(4 * 32), 256, 0, stream>>>(
      feat, nullptr, wfc, b_fc, r1, st1, 0, NN, NN / 64, 32);
  // K2: gfeat1 = relu(W_gc@gf+b) -> r2 [b][p][128], stats1 groups 16..31
  gemm_kern<128, 128, 0, true><<<dim3(4 * 192), 256, 0, stream>>>(
      gf, nullptr, wgc, b_gc, r2, st1, 16, PP, PP / 64, 192);

  fold1_kern<<<4, 256, 0, stream>>>(st1, g1, be1, W_w1, b_w1, w1p, b1p);

  // K4: x2 = relu(W1'(GN1-folded) @ concat(r1,r2)) -> x2, stats2 (LDS-free)
  gemm_kern<256, 256, 1, true><<<dim3(4 * 256), 256, 0, stream>>>(
      r1, r2, w1p, b1p, x2, st2, 0, PP, PP / 64, 256);

  // K3: go_raw = W_fo@gfo+b (no relu) -> gor (overwrites r2), stats3 on raw
  gemm_kern<256, 256, 0, false><<<dim3(4 * 192), 256, 0, stream>>>(
      gfo, nullptr, wfo, b_fo, gor, st3, 0, PP, PP / 64, 192);

  fold23_kern<<<4, 256, 0, stream>>>(st2, st3, g2, be2, W_w2, b_w2, g3, be3, w2p, b2p, s3t);

  // K5: scores (GN2-folded) + mask + softmax + sum_k relu(GN3(go))*w -> out
  k5_kern<<<dim3(4 * 192), 256, 0, stream>>>(x2, gor, w2p, b2p, s3t, cnt, out, 192);
}

// Round 4
// 774.968 us; speedup vs baseline: 1.3988x; 1.3988x over previous
//
#include <hip/hip_runtime.h>
#include <stdint.h>

#define DEVI __device__ __forceinline__

typedef __attribute__((ext_vector_type(4))) int    i32x4;
typedef __attribute__((ext_vector_type(4))) float  f32x4;
typedef __attribute__((ext_vector_type(8))) __bf16 bf16x8;

static constexpr int BB = 4, NN = 2048, KK = 32, PP = NN * KK;  // P per batch
static constexpr float GEPS = 1e-5f;

DEVI unsigned short f2bf(float f) {
  unsigned u = __builtin_bit_cast(unsigned, f);
  return (unsigned short)((u + 0x7FFFu + ((u >> 16) & 1u)) >> 16);
}
DEVI float bf2f(unsigned short h) {
  unsigned u = (unsigned)h << 16;
  return __builtin_bit_cast(float, u);
}
DEVI uint2 pack4(float a, float b, float c, float d) {
  return make_uint2((unsigned)f2bf(a) | ((unsigned)f2bf(b) << 16),
                    (unsigned)f2bf(c) | ((unsigned)f2bf(d) << 16));
}
DEVI void mfma16(f32x4& d, i32x4 a, i32x4 b) {
  // A[m=lane&15][k=8*(lane>>4)+j], B[k][n=lane&15], D[m=(lane>>4)*4+reg][n=lane&15].
  d = __builtin_amdgcn_mfma_f32_16x16x32_bf16(
      __builtin_bit_cast(bf16x8, a), __builtin_bit_cast(bf16x8, b), d, 0, 0, 0);
}

// ---------------- prep: convert f32 weights to bf16 ----------------
__global__ void prep_kern(const float* Wfc, const float* Wgc, const float* Wfo,
                          unsigned short* dWfc, unsigned short* dWgc, unsigned short* dWfo) {
  int i = blockIdx.x * 256 + threadIdx.x;
  if (i < 16384)       dWfc[i] = f2bf(Wfc[i]);
  else if (i < 32768)  dWgc[i - 16384] = f2bf(Wgc[i - 16384]);
  else if (i < 98304)  dWfo[i - 32768] = f2bf(Wfo[i - 32768]);
}

// ---------------- generic fused GEMM ----------------
// out[b][p][COUT] (bf16) = act( W[COUT][CIN] @ in[b][CIN][p]  + bias )
// 512 threads = 8 waves; wave w owns output channels [w*COUT/8, +COUT/8).
// W held in registers (<=64 VGPR); input tile staged in LDS.
// MODE 0: srcA = f32 channel-major [b][CIN][P]; transpose+bf16-pack into LDS.
// MODE 1: srcA = r1 bf16 [b][n][128] (k-broadcast), srcB = r2 bf16 [b][p][128];
//         concat-staged to LDS; W/bias per-batch (folded).
template<int CIN, int COUT, int MODE, bool RELU>
__global__ __launch_bounds__(512, 4)
void gemm_kern(const void* srcA, const void* srcB,
               const unsigned short* Wmat, const float* bias,
               unsigned short* out, float* stats, int group_base,
               int P, int tiles_per_b, int nblk) {
  constexpr int MW = COUT / 8;    // o-range per wave
  constexpr int MF = MW / 16;     // m-fragments per wave (1 or 2)
  constexpr int KS = CIN / 32;    // k-steps
  constexpr int CINP = CIN + 8;   // padded LDS pitch (shorts); rows 16B-aligned
  __shared__ unsigned short tile[64 * CINP];

  const int tid = threadIdx.x;
  const int lane = tid & 63, w = tid >> 6;
  const int l15 = lane & 15, lg = lane >> 4;
  const int b = blockIdx.x / nblk, blk = blockIdx.x % nblk;

  const unsigned short* Wb = (MODE == 1) ? (Wmat + (size_t)b * COUT * CIN) : Wmat;
  const float* biasb = (MODE == 1) ? (bias + b * COUT) : bias;

  // A fragments (weights) resident in registers for the whole kernel
  i32x4 a[KS][MF];
#pragma unroll
  for (int ks = 0; ks < KS; ++ks)
#pragma unroll
    for (int mf = 0; mf < MF; ++mf)
      a[ks][mf] = *(const i32x4*)(Wb + (size_t)(w * MW + mf * 16 + l15) * CIN + ks * 32 + lg * 8);

  f32x4 bi[MF];
#pragma unroll
  for (int mf = 0; mf < MF; ++mf)
    bi[mf] = *(const f32x4*)(biasb + w * MW + mf * 16 + lg * 4);

  float ssum[MF], ssq[MF];
#pragma unroll
  for (int mf = 0; mf < MF; ++mf) { ssum[mf] = 0.f; ssq[mf] = 0.f; }

  for (int t = blk; t < tiles_per_b; t += nblk) {
    const int p0 = t * 64;
    if (MODE == 0) {
      // transpose-stage: per pass, thread loads 4 ch x 4 pos (4 f32x4), packs
      // to bf16, writes uint2 rows. 512 threads cover 64 pos x 128 ch / pass.
      const float* src = (const float*)srcA + (size_t)b * CIN * P + p0;
      const int cq = tid >> 4, pq = tid & 15;  // cq 0..31, pq 0..15
#pragma unroll
      for (int pass = 0; pass < CIN / 128; ++pass) {
        const int c0 = pass * 128 + cq * 4;
        f32x4 v[4];
#pragma unroll
        for (int i = 0; i < 4; ++i)
          v[i] = *(const f32x4*)(src + (size_t)(c0 + i) * (size_t)P + pq * 4);
#pragma unroll
        for (int jj = 0; jj < 4; ++jj)
          *(uint2*)&tile[(pq * 4 + jj) * CINP + c0] =
              pack4(v[0][jj], v[1][jj], v[2][jj], v[3][jj]);
      }
    } else {
      // concat-stage: row p = tid>>3 (64 rows), 8 threads/row x 4 chunks of 16B
      const unsigned short* r1b = (const unsigned short*)srcA + (size_t)b * NN * 128;
      const unsigned short* r2b = (const unsigned short*)srcB + (size_t)b * PP * 128;
      const int p = tid >> 3;
#pragma unroll
      for (int j = 0; j < 4; ++j) {
        const int chunk = j * 8 + (tid & 7);  // 0..31
        const int c = chunk * 8;              // shorts
        const unsigned short* sp;
        if (c < 128) {
          const int n = (p0 + p) >> 5;
          sp = r1b + (size_t)n * 128 + c;
        } else {
          sp = r2b + (size_t)(p0 + p) * 128 + (c - 128);
        }
        *(uint4*)&tile[p * CINP + c] = *(const uint4*)sp;
      }
    }
    __syncthreads();

    f32x4 acc[MF][4];
#pragma unroll
    for (int mf = 0; mf < MF; ++mf)
#pragma unroll
      for (int nf = 0; nf < 4; ++nf) acc[mf][nf] = f32x4{0.f, 0.f, 0.f, 0.f};

#pragma unroll
    for (int ks = 0; ks < KS; ++ks) {
      i32x4 b4[4];
#pragma unroll
      for (int nf = 0; nf < 4; ++nf)
        b4[nf] = *(const i32x4*)&tile[(nf * 16 + l15) * CINP + ks * 32 + lg * 8];
#pragma unroll
      for (int mf = 0; mf < MF; ++mf)
#pragma unroll
        for (int nf = 0; nf < 4; ++nf) mfma16(acc[mf][nf], a[ks][mf], b4[nf]);
    }
    __syncthreads();  // all waves done reading tile before restage

    // epilogue: bias (+relu), stats partials, packed bf16 store (pos-major)
#pragma unroll
    for (int mf = 0; mf < MF; ++mf) {
      const int o4 = w * MW + mf * 16 + lg * 4;
#pragma unroll
      for (int nf = 0; nf < 4; ++nf) {
        const int p = p0 + nf * 16 + l15;
        float y0 = acc[mf][nf][0] + bi[mf][0];
        float y1 = acc[mf][nf][1] + bi[mf][1];
        float y2 = acc[mf][nf][2] + bi[mf][2];
        float y3 = acc[mf][nf][3] + bi[mf][3];
        if (RELU) {
          y0 = fmaxf(y0, 0.f); y1 = fmaxf(y1, 0.f);
          y2 = fmaxf(y2, 0.f); y3 = fmaxf(y3, 0.f);
        }
        ssum[mf] += y0 + y1 + y2 + y3;
        ssq[mf] += y0 * y0 + y1 * y1 + y2 * y2 + y3 * y3;
        *(uint2*)(out + ((size_t)b * P + p) * COUT + o4) = pack4(y0, y1, y2, y3);
      }
    }
  }

  // block-level stats reduction -> global atomics
#pragma unroll
  for (int mf = 0; mf < MF; ++mf) {
    float s = ssum[mf], q = ssq[mf];
#pragma unroll
    for (int d = 1; d < 16; d <<= 1) { s += __shfl_xor(s, d); q += __shfl_xor(q, d); }
    if (l15 == 0) {
      int g = group_base + ((w * MW + mf * 16 + lg * 4) >> 3);
      atomicAdd(&stats[(b * 32 + g) * 2 + 0], s);
      atomicAdd(&stats[(b * 32 + g) * 2 + 1], q);
    }
  }
}

// ---------------- fold kernels ----------------
__global__ void fold1_kern(const float* st1, const float* g1, const float* be1,
                           const float* W_w1, const float* b_w1,
                           unsigned short* W1p, float* b1p) {
  int b = blockIdx.x, tid = threadIdx.x;
  __shared__ float s_l[256], t_l[256];
  {
    int c = tid, g = c >> 3;
    float cnt = (g < 16) ? (8.f * NN) : (8.f * NN * KK);
    float su = st1[(b * 32 + g) * 2], sq = st1[(b * 32 + g) * 2 + 1];
    float mean = su / cnt;
    float var = fmaxf(sq / cnt - mean * mean, 0.f);
    float s = g1[c] * rsqrtf(var + GEPS);
    s_l[c] = s; t_l[c] = be1[c] - mean * s;
  }
  __syncthreads();
  int o = tid;
  float acc = b_w1[o];
  for (int c4 = 0; c4 < 64; ++c4) {
    float4 wv = *(const float4*)(W_w1 + o * 256 + c4 * 4);
    *(uint2*)&W1p[((size_t)b * 256 + o) * 256 + c4 * 4] =
        pack4(wv.x * s_l[c4 * 4], wv.y * s_l[c4 * 4 + 1],
              wv.z * s_l[c4 * 4 + 2], wv.w * s_l[c4 * 4 + 3]);
    acc += wv.x * t_l[c4 * 4] + wv.y * t_l[c4 * 4 + 1] +
           wv.z * t_l[c4 * 4 + 2] + wv.w * t_l[c4 * 4 + 3];
  }
  b1p[b * 256 + o] = acc;
}

__global__ void fold23_kern(const float* st2, const float* st3,
                            const float* g2, const float* be2,
                            const float* W_w2, const float* b_w2,
                            const float* g3, const float* be3,
                            unsigned short* W2p, float* b2p, float* s3t3) {
  int b = blockIdx.x, tid = threadIdx.x;
  __shared__ float s_l[256], t_l[256];
  {
    int c = tid, g = c >> 3;
    float cnt = 8.f * NN * KK;
    float su = st2[(b * 32 + g) * 2], sq = st2[(b * 32 + g) * 2 + 1];
    float mean = su / cnt;
    float var = fmaxf(sq / cnt - mean * mean, 0.f);
    float s = g2[c] * rsqrtf(var + GEPS);
    s_l[c] = s; t_l[c] = be2[c] - mean * s;

    float su3 = st3[(b * 32 + g) * 2], sq3 = st3[(b * 32 + g) * 2 + 1];
    float mean3 = su3 / cnt;
    float var3 = fmaxf(sq3 / cnt - mean3 * mean3, 0.f);
    float s3 = g3[c] * rsqrtf(var3 + GEPS);
    s3t3[(b * 256 + c) * 2 + 0] = s3;
    s3t3[(b * 256 + c) * 2 + 1] = be3[c] - mean3 * s3;
  }
  __syncthreads();
  int o = tid;
  float acc = b_w2[o];
  for (int c4 = 0; c4 < 64; ++c4) {
    float4 wv = *(const float4*)(W_w2 + o * 256 + c4 * 4);
    *(uint2*)&W2p[((size_t)b * 256 + o) * 256 + c4 * 4] =
        pack4(wv.x * s_l[c4 * 4], wv.y * s_l[c4 * 4 + 1],
              wv.z * s_l[c4 * 4 + 2], wv.w * s_l[c4 * 4 + 3]);
    acc += wv.x * t_l[c4 * 4] + wv.y * t_l[c4 * 4 + 1] +
           wv.z * t_l[c4 * 4 + 2] + wv.w * t_l[c4 * 4 + 3];
  }
  b2p[b * 256 + o] = acc;
}

// ---------------- K5: scores GEMM + masked softmax + weighted sum ----------------
// 512 threads = 8 waves, wave w owns 32 o-channels. W2 in regs; x2 A-frags read
// direct from global (identical across waves -> L1 broadcast); gor tile staged
// in LDS (coalesced fetch; scalar LDS reads in epilogue).
__global__ __launch_bounds__(512, 4)
void k5_kern(const unsigned short* x2t, const unsigned short* gor,
             const unsigned short* W2p, const float* b2p,
             const float* s3t3, const int* count, float* out, int nblk) {
  constexpr int GP = 264;
  __shared__ unsigned short gt[64 * GP];
  const int tid = threadIdx.x, lane = tid & 63, w = tid >> 6;
  const int l15 = lane & 15, lg = lane >> 4;
  const int b = blockIdx.x / nblk, blk = blockIdx.x % nblk;

  const unsigned short* Wb = W2p + (size_t)b * 65536;

  // B-operand W2 rows for this wave's 32 channels, resident (64 VGPR)
  i32x4 wb[8][2];
#pragma unroll
  for (int ks = 0; ks < 8; ++ks)
#pragma unroll
    for (int of = 0; of < 2; ++of)
      wb[ks][of] = *(const i32x4*)(Wb + (size_t)(w * 32 + of * 16 + l15) * 256 + ks * 32 + lg * 8);

  float bia[2], s3v[2], t3v[2];
#pragma unroll
  for (int of = 0; of < 2; ++of) {
    int o = w * 32 + of * 16 + l15;
    bia[of] = b2p[b * 256 + o];
    s3v[of] = s3t3[(b * 256 + o) * 2 + 0];
    t3v[of] = s3t3[(b * 256 + o) * 2 + 1];
  }

  const unsigned short* xb = x2t + (size_t)b * PP * 256;
  const unsigned short* gb = gor + (size_t)b * PP * 256;

  for (int t = blk; t < 1024; t += nblk) {
    const int p0 = t * 64, n0 = p0 >> 5;

    // stage gor tile [64][256] -> gt: row p = tid>>3, 8 threads x 4 chunks
    {
      const unsigned short* gsrc = gb + (size_t)p0 * 256;
      const int p = tid >> 3;
#pragma unroll
      for (int j = 0; j < 4; ++j) {
        const int c = (j * 8 + (tid & 7)) * 8;
        *(uint4*)&gt[p * GP + c] = *(const uint4*)(gsrc + (size_t)p * 256 + c);
      }
    }
    __syncthreads();

    f32x4 acc[4][2];  // [pf][of]
#pragma unroll
    for (int pf = 0; pf < 4; ++pf)
#pragma unroll
      for (int of = 0; of < 2; ++of) acc[pf][of] = f32x4{0.f, 0.f, 0.f, 0.f};

#pragma unroll
    for (int ks = 0; ks < 8; ++ks) {
      i32x4 af[4];
#pragma unroll
      for (int pf = 0; pf < 4; ++pf)
        af[pf] = *(const i32x4*)(xb + (size_t)(p0 + pf * 16 + l15) * 256 + ks * 32 + lg * 8);
#pragma unroll
      for (int pf = 0; pf < 4; ++pf)
#pragma unroll
        for (int of = 0; of < 2; ++of) mfma16(acc[pf][of], af[pf], wb[ks][of]);
    }

    const int cnt0 = max(count[b * NN + n0], 1);
    const int cnt1 = max(count[b * NN + n0 + 1], 1);
#pragma unroll
    for (int of = 0; of < 2; ++of) {
      const int o = w * 32 + of * 16 + l15;
      float res[2];
#pragma unroll
      for (int pair = 0; pair < 2; ++pair) {
        const int cnt = pair ? cnt1 : cnt0;
        float sc[2][4];
#pragma unroll
        for (int ph = 0; ph < 2; ++ph)
#pragma unroll
          for (int r = 0; r < 4; ++r) {
            int k = ph * 16 + lg * 4 + r;
            float v = acc[pair * 2 + ph][of][r] + bia[of];
            sc[ph][r] = (k < cnt) ? v : -1e9f;
          }
        float m = sc[0][0];
#pragma unroll
        for (int ph = 0; ph < 2; ++ph)
#pragma unroll
          for (int r = 0; r < 4; ++r) m = fmaxf(m, sc[ph][r]);
        m = fmaxf(m, __shfl_xor(m, 16));
        m = fmaxf(m, __shfl_xor(m, 32));
        float den = 0.f, con = 0.f;
#pragma unroll
        for (int ph = 0; ph < 2; ++ph)
#pragma unroll
          for (int r = 0; r < 4; ++r) {
            float e = __expf(sc[ph][r] - m);
            int prel = pair * 32 + ph * 16 + lg * 4 + r;
            float g = bf2f(gt[prel * GP + o]);
            g = fmaxf(s3v[of] * g + t3v[of], 0.f);
            den += e; con += e * g;
          }
        den += __shfl_xor(den, 16); con += __shfl_xor(con, 16);
        den += __shfl_xor(den, 32); con += __shfl_xor(con, 32);
        res[pair] = con / den;
      }
      if (lg == 0)
        *(float2*)(out + (size_t)(b * 256 + o) * NN + n0) = make_float2(res[0], res[1]);
    }
    __syncthreads();  // gt consumed; safe to restage
  }
}

// ---------------- launch ----------------
extern "C" void kernel_launch(void* const* d_in, const int* in_sizes, int n_in,
                              void* d_out, int out_size, void* d_ws, size_t ws_size,
                              hipStream_t stream) {
  const float* feat = (const float*)d_in[0];
  const float* gf   = (const float*)d_in[1];
  const float* gfo  = (const float*)d_in[2];
  const int*   cnt  = (const int*)d_in[3];
  const float* W_fc = (const float*)d_in[4];
  const float* b_fc = (const float*)d_in[5];
  const float* W_gc = (const float*)d_in[6];
  const float* b_gc = (const float*)d_in[7];
  const float* g1   = (const float*)d_in[8];
  const float* be1  = (const float*)d_in[9];
  const float* W_w1 = (const float*)d_in[10];
  const float* b_w1 = (const float*)d_in[11];
  const float* g2   = (const float*)d_in[12];
  const float* be2  = (const float*)d_in[13];
  const float* W_w2 = (const float*)d_in[14];
  const float* b_w2 = (const float*)d_in[15];
  const float* W_fo = (const float*)d_in[16];
  const float* b_fo = (const float*)d_in[17];
  const float* g3   = (const float*)d_in[18];
  const float* be3  = (const float*)d_in[19];
  float* out = (float*)d_out;
  char* ws = (char*)d_ws;

  constexpr size_t ST1 = 0, ST2 = 1024, ST3 = 2048;
  constexpr size_t WFC = 4096;
  constexpr size_t WGC = WFC + 32768;
  constexpr size_t WFO = WGC + 32768;
  constexpr size_t W1P = WFO + 131072;
  constexpr size_t B1P = W1P + 524288;
  constexpr size_t W2P = B1P + 4096;
  constexpr size_t B2P = W2P + 524288;
  constexpr size_t S3T = B2P + 4096;
  constexpr size_t R1  = 2097152;
  constexpr size_t X2  = R1 + 2097152;
  constexpr size_t R2  = X2 + 134217728;
  constexpr size_t GOR = R2;  // go_raw overwrites r2 (written after K4 consumed r2)
  constexpr size_t WS_NEED = GOR + 134217728;
  if (ws_size < WS_NEED) return;

  float* st1 = (float*)(ws + ST1);
  float* st2 = (float*)(ws + ST2);
  float* st3 = (float*)(ws + ST3);
  unsigned short* wfc = (unsigned short*)(ws + WFC);
  unsigned short* wgc = (unsigned short*)(ws + WGC);
  unsigned short* wfo = (unsigned short*)(ws + WFO);
  unsigned short* w1p = (unsigned short*)(ws + W1P);
  float* b1p = (float*)(ws + B1P);
  unsigned short* w2p = (unsigned short*)(ws + W2P);
  float* b2p = (float*)(ws + B2P);
  float* s3t = (float*)(ws + S3T);
  unsigned short* r1 = (unsigned short*)(ws + R1);
  unsigned short* x2 = (unsigned short*)(ws + X2);
  unsigned short* r2 = (unsigned short*)(ws + R2);
  unsigned short* gor = (unsigned short*)(ws + GOR);

  hipMemsetAsync(ws, 0, 3072, stream);
  prep_kern<<<384, 256, 0, stream>>>(W_fc, W_gc, W_fo, wfc, wgc, wfo);

  // K1: feat1 = relu(W_fc@feat+b) -> r1 [b][n][128], stats1 groups 0..15
  gemm_kern<128, 128, 0, true><<<dim3(4 * 32), 512, 0, stream>>>(
      feat, nullptr, wfc, b_fc, r1, st1, 0, NN, NN / 64, 32);
  // K2: gfeat1 = relu(W_gc@gf+b) -> r2 [b][p][128], stats1 groups 16..31
  gemm_kern<128, 128, 0, true><<<dim3(4 * 128), 512, 0, stream>>>(
      gf, nullptr, wgc, b_gc, r2, st1, 16, PP, PP / 64, 128);

  fold1_kern<<<4, 256, 0, stream>>>(st1, g1, be1, W_w1, b_w1, w1p, b1p);

  // K4: x2 = relu(W1'(GN1-folded) @ concat(r1,r2)) -> x2, stats2
  gemm_kern<256, 256, 1, true><<<dim3(4 * 128), 512, 0, stream>>>(
      r1, r2, w1p, b1p, x2, st2, 0, PP, PP / 64, 128);

  // K3: go_raw = W_fo@gfo+b (no relu) -> gor (overwrites r2), stats3 on raw
  gemm_kern<256, 256, 0, false><<<dim3(4 * 128), 512, 0, stream>>>(
      gfo, nullptr, wfo, b_fo, gor, st3, 0, PP, PP / 64, 128);

  fold23_kern<<<4, 256, 0, stream>>>(st2, st3, g2, be2, W_w2, b_w2, g3, be3, w2p, b2p, s3t);

  // K5: scores (GN2-folded) + mask + softmax + sum_k relu(GN3(go))*w -> out
  k5_kern<<<dim3(4 * 128), 512, 0, stream>>>(x2, gor, w2p, b2p, s3t, cnt, out, 128);
}